// Round 6
// baseline (306.428 us; speedup 1.0000x reference)
//
#include <hip/hip_runtime.h>
#include <hip/hip_bf16.h>

typedef __attribute__((ext_vector_type(8))) short short8;
typedef __attribute__((ext_vector_type(4))) short short4_;
typedef __attribute__((ext_vector_type(4))) float float4_;
typedef __attribute__((ext_vector_type(4))) unsigned int uint4_;

#define CH 64
#define HH 256
#define WW 256
#define HW (HH*WW)
#define CHW (CH*HW)

#define TW 16
#define TH 8
#define XPW 20
#define XPH 12
#define NXP 240        // x/qkv halo set (halo 2)
#define OPW 18
#define OPH 10
#define NOP 180        // out1 set (halo 1)

// Strides (shorts). All buffers use 8-short (16 B) granules with XOR swizzles
// so b128 rows stay 16B-aligned while bank starts spread.
#define XLS 64         // x tile: [240][64], granule ^= (pix>>2)&7
#define KQS2 32        // k/q QK buffers: [*][32], granule ^= (p^(p>>2))&3
#define VSS 16         // vbuf: [240][16], granule ^= (p^(p>>2))&1
#define O1S 64         // o1b: [180][64], granule ^= pix&7 (round-5 layout)
#define TSF 33         // tbuf row stride (floats)

// LDS regions (shorts), peak = 15360 -> 30720 B (+320 runtime) -> 5 blocks/CU
// (was 38400 B -> 4 blocks; occupancy was the binding resource, rounds 2-5).
//  xls   [0, 15360)
//  QK:   kbuf2 [0, 7680) = [240][32]sw ; qbuf2 [7680, 13440) = [180][32]sw
//  V:    vbuf  [0, 3840) = [240][16]sw ; o1b [3840, 15360) = [180][64]sw
//  epi:  tbuf  [0, 8448)  (floats [128][33])
#define QB2_OFF 7680
#define O1_OFF  3840
#define SMEM_SHORTS 15360

// ws layout: wsq bf16 [0,24576) ; wsm bf16 [24576, 98304)
#define WSQ_SHORTS 12288
#define WSM_SHORTS 36864

__device__ __forceinline__ float b2f(unsigned short u) {
    return __uint_as_float(((unsigned)u) << 16);
}
__device__ __forceinline__ float blo(unsigned u) {      // even channel of pair
    return __uint_as_float(u << 16);
}
__device__ __forceinline__ float bhi(unsigned u) {      // odd channel of pair
    return __uint_as_float(u & 0xffff0000u);
}
__device__ __forceinline__ short f2bs(float f) {
    __hip_bfloat16 h = __float2bfloat16(f);
    short s; __builtin_memcpy(&s, &h, 2); return s;
}
__device__ __forceinline__ unsigned pack2(float a, float b) {
    return (unsigned)(unsigned short)f2bs(a) |
           ((unsigned)(unsigned short)f2bs(b) << 16);
}

// xls: channel c of halo pixel pix
__device__ __forceinline__ int xls_idx(int pix, int c) {
    int g = ((c >> 3) ^ ((pix >> 2) & 7));
    return pix * XLS + g * 8 + (c & 7);
}
// k/q granule swizzle key (2 bits) — changes under both lane-step (p+=1 in
// dot reads) and quad-step (p+=4 in gemm stores), spreading bank starts
__device__ __forceinline__ int kqswz(int p) {
    return (p ^ (p >> 2)) & 3;
}
// o1b: channel c of interior pixel pix
__device__ __forceinline__ int o1_idx(int pix, int c) {
    int g = (((c >> 3) ^ pix) & 7);
    return pix * O1S + g * 8 + (c & 7);
}
// vbuf: channel c (0..15) of halo pixel p
__device__ __forceinline__ int v_idx(int p, int c) {
    int g = (((c >> 3) ^ p ^ (p >> 2)) & 1);
    return p * VSS + g * 8 + (c & 7);
}

#if defined(__has_builtin)
#if __has_builtin(__builtin_amdgcn_fdot2_f32_bf16)
#define HAS_BF16_DOT2 1
#endif
#endif
#ifdef HAS_BF16_DOT2
typedef __bf16 bf16x2 __attribute__((ext_vector_type(2)));
__device__ __forceinline__ float dot2acc(unsigned a, unsigned b, float acc) {
    return __builtin_amdgcn_fdot2_f32_bf16(__builtin_bit_cast(bf16x2, a),
                                           __builtin_bit_cast(bf16x2, b),
                                           acc, false);
}
#else
__device__ __forceinline__ float dot2acc(unsigned a, unsigned b, float acc) {
    acc += blo(a) * blo(b);
    acc += bhi(a) * bhi(b);
    return acc;
}
#endif

// ---- prep: pack wqkv/wmlp to bf16 in exact B-fragment order -----------------
__global__ void prep_pack(const float* __restrict__ wqkv,
                          const float* __restrict__ wmlp,
                          short* __restrict__ wsq, short* __restrict__ wsm) {
    int idx = blockIdx.x * blockDim.x + threadIdx.x;
    int stride = gridDim.x * blockDim.x;
    for (int e = idx; e < WSQ_SHORTS; e += stride) {
        int j = e & 7, lane = (e >> 3) & 63;
        int ks = (e >> 9) & 1, q16 = (e >> 10) & 3, sec = e >> 12;
        int row = sec*64 + q16*16 + (lane & 15);
        int kk  = ks*32 + (lane >> 4)*8 + j;
        wsq[e] = f2bs(wqkv[(size_t)row*64 + kk]);
    }
    for (int e = idx; e < WSM_SHORTS; e += stride) {
        int j = e & 7, lane = (e >> 3) & 63;
        int rest = e >> 9;            // 0..71
        int nt = rest / 18, ks = rest % 18;
        int o   = nt*16 + (lane & 15);
        int cin = (ks & 1)*32 + (lane >> 4)*8 + j;
        int tap = ks >> 1;
        wsm[e] = f2bs(wmlp[(size_t)o*576 + cin*9 + tap]);
    }
}

// ---- fused kernel -----------------------------------------------------------
// __launch_bounds__(256,3): (256,4) pinned the allocator at the 64-VGPR step
// and spilled (+250 MB HBM, round-1 evidence). Round-5's conv-weight
// prefetch (cw[4]+nw[4]) also spilled (FETCH/WRITE +45 MB symmetric) ->
// reverted. LDS 30720 B -> 5 blocks/CU; VGPR must stay <=102 for that cap.
__global__ __launch_bounds__(256, 3) void fused_mfma(
    const float* __restrict__ x, const short* __restrict__ wsq,
    const float* __restrict__ bqkv, const short* __restrict__ wsm,
    float* __restrict__ out)
{
    __shared__ __align__(16) short smem[SMEM_SHORTS];
    short* xls   = smem;                             // phase X only (swizzled)
    short* kbuf2 = smem;                             // [240][32]sw QK rounds
    short* qbuf2 = smem + QB2_OFF;                   // [180][32]sw QK rounds
    short* vbuf  = smem;                             // [240][16]sw V rounds
    short* o1b   = smem + O1_OFF;                    // [180][64]sw V/conv
    float* tbuf  = (float*)smem;                     // [128][33] epilogue

    const int t    = threadIdx.x;
    const int w    = t >> 6;
    const int lane = t & 63;
    const int n16  = lane & 15;
    const int quad = lane >> 4;

    // XCD-chunk swizzle (round-2 verified: FETCH 260->58 MB): XCD k owns a
    // contiguous chunk of tiles. 2048 % 8 == 0 -> bijective.
    const int d   = blockIdx.x + (blockIdx.y << 4) + (blockIdx.z << 9);
    const int nn  = ((d & 7) << 8) | (d >> 3);
    const int b   = nn >> 9;
    const int rem = nn & 511;
    const int gy0 = (rem >> 4) * TH;
    const int gx0 = (rem & 15) * TW;
    const float* xb = x + (size_t)b * CHW;

    // NOTE: all 4 waves process exactly 4 M-tiles (16th tile is a clamped
    // dummy) so every register-array index is compile-time static.
    // Dynamic-bound loops over register arrays caused scratch spills.

    // ---- phase X: stage x halo into LDS bf16. Channel-PAIR packed b32
    // writes + granule swizzle (round-4 verified: conflicts 1.87e7 -> 6.7e6;
    // the residual ~3.3k cyc/block here is structural at b32 width: all
    // lane-varying bank terms are multiples of 4 -> 8-way; ~2% cost, accept).
    for (int slot = t; slot < 32*12*6; slot += 256) {
        int s6 = slot % 6, y = (slot / 6) % 12, c2 = slot / 72;
        int c  = c2 * 2;
        int gy = gy0 - 2 + y;
        int gxb = gx0 - 4 + s6*4;
        float v0[4], v1[4];
        bool gyok = (unsigned)gy < HH;
        if (gyok && gxb >= 0 && gxb + 3 < WW) {
            float4_ f0 = *(const float4_*)(xb + (size_t)c*HW + gy*WW + gxb);
            float4_ f1 = *(const float4_*)(xb + (size_t)(c+1)*HW + gy*WW + gxb);
            #pragma unroll
            for (int i = 0; i < 4; ++i) { v0[i] = f0[i]; v1[i] = f1[i]; }
        } else {
            #pragma unroll
            for (int i = 0; i < 4; ++i) {
                int gx = gxb + i;
                bool ok = gyok && (unsigned)gx < WW;
                v0[i] = ok ? xb[(size_t)c*HW + gy*WW + gx] : 0.f;
                v1[i] = ok ? xb[(size_t)(c+1)*HW + gy*WW + gx] : 0.f;
            }
        }
        #pragma unroll
        for (int i = 0; i < 4; ++i) {
            int pxc = s6*4 + i - 2;
            if ((unsigned)pxc < XPW)
                *(unsigned*)&xls[xls_idx(y*XPW + pxc, c)] = pack2(v0[i], v1[i]);
        }
    }
    __syncthreads();

    // OOB bitmask: bit(i*4+r) -> halo pixel (w*4+i)*16 + quad*4 + r
    unsigned okbits = 0;
    #pragma unroll
    for (int i = 0; i < 4; ++i)
        #pragma unroll
        for (int r = 0; r < 4; ++r) {
            int p = (w*4 + i)*16 + quad*4 + r;
            if (p < NXP) {
                int gy = gy0 - 2 + p / XPW, gx = gx0 - 2 + p % XPW;
                if (((unsigned)gy < HH) && ((unsigned)gx < WW))
                    okbits |= 1u << (i*4 + r);
            }
        }

    // ---- A-frags (swizzled reads, static-indexed) + residual capture
    short8 afr[4][2];
    #pragma unroll
    for (int i = 0; i < 4; ++i) {
        int p = (w*4 + i)*16 + n16;
        int pr = (p < NXP) ? p : 0;        // clamped dummy for wave3/i3
        #pragma unroll
        for (int ks = 0; ks < 2; ++ks)
            afr[i][ks] = *(const short8*)&xls[xls_idx(pr, ks*32 + quad*8)];
    }
    // per-thread attention pixel
    const int op_py = t / OPW, op_px = t % OPW;
    const int ogy = gy0 - 1 + op_py, ogx = gx0 - 1 + op_px;
    const bool oin = (t < NOP) && ((unsigned)ogy < HH) && ((unsigned)ogx < WW);
    const int xpix = (op_py + 1)*XPW + (op_px + 1);
    short8 resi[8];
    if (t < NOP) {
        #pragma unroll
        for (int g = 0; g < 8; ++g)
            resi[g] = *(const short8*)&xls[xls_idx(xpix, g*8)];
    }
    __syncthreads();   // xls dead; k/q regions may now be written

    // B-fragment loader (global, L2-resident 24 KB)
    auto wload = [&](int sec, int q16, int ks) -> short8 {
        return *(const short8*)&wsq[(((sec*4 + q16)*2 + ks) << 9) + lane*8];
    };
    // gemm 16 out-ch into kbuf2 (granule-swizzled), OOB rows zeroed
    auto gemm_k = [&](short8 b0, short8 b1, float bias, int coff) {
        #pragma unroll
        for (int i = 0; i < 4; ++i) {
            float4_ c = {0.f, 0.f, 0.f, 0.f};
            c = __builtin_amdgcn_mfma_f32_16x16x32_bf16(afr[i][0], b0, c, 0, 0, 0);
            c = __builtin_amdgcn_mfma_f32_16x16x32_bf16(afr[i][1], b1, c, 0, 0, 0);
            #pragma unroll
            for (int r = 0; r < 4; ++r) {
                int p = (w*4 + i)*16 + quad*4 + r;
                bool ok = (okbits >> (i*4 + r)) & 1u;
                if (p < NXP) {
                    int cc = coff + n16;
                    int idx = p*KQS2 + ((((cc >> 3) ^ kqswz(p)) & 3) << 3) + (cc & 7);
                    kbuf2[idx] = ok ? f2bs(c[r] + bias) : (short)0;
                }
            }
        }
    };
    // gemm 16 out-ch into vbuf (granule-swizzled stride VSS)
    auto gemm_v = [&](short8 b0, short8 b1, float bias) {
        #pragma unroll
        for (int i = 0; i < 4; ++i) {
            float4_ c = {0.f, 0.f, 0.f, 0.f};
            c = __builtin_amdgcn_mfma_f32_16x16x32_bf16(afr[i][0], b0, c, 0, 0, 0);
            c = __builtin_amdgcn_mfma_f32_16x16x32_bf16(afr[i][1], b1, c, 0, 0, 0);
            #pragma unroll
            for (int r = 0; r < 4; ++r) {
                int p = (w*4 + i)*16 + quad*4 + r;
                bool ok = (okbits >> (i*4 + r)) & 1u;
                if (p < NXP)
                    vbuf[v_idx(p, n16)] = ok ? f2bs(c[r] + bias) : (short)0;
            }
        }
    };
    // gemm 16 out-ch of q, stored interior-compressed (180 rows)
    auto gemm_q = [&](short8 b0, short8 b1, float bias, int coff) {
        #pragma unroll
        for (int i = 0; i < 4; ++i) {
            float4_ c = {0.f, 0.f, 0.f, 0.f};
            c = __builtin_amdgcn_mfma_f32_16x16x32_bf16(afr[i][0], b0, c, 0, 0, 0);
            c = __builtin_amdgcn_mfma_f32_16x16x32_bf16(afr[i][1], b1, c, 0, 0, 0);
            #pragma unroll
            for (int r = 0; r < 4; ++r) {
                int p = (w*4 + i)*16 + quad*4 + r;
                int py = p / XPW, px = p % XPW;
                if ((unsigned)(py - 1) < (unsigned)OPH &&
                    (unsigned)(px - 1) < (unsigned)OPW) {
                    int op = (py - 1)*OPW + (px - 1);
                    int cc = coff + n16;
                    int idx = op*KQS2 + ((((cc >> 3) ^ kqswz(op)) & 3) << 3) + (cc & 7);
                    qbuf2[idx] = f2bs(c[r] + bias);
                }
            }
        }
    };

    // ---- QK: 2 rounds x 32 channels
    float dots[9];
    #pragma unroll
    for (int n2 = 0; n2 < 9; ++n2) dots[n2] = 0.f;

    short8 pw0 = wload(0,0,0), pw1 = wload(0,0,1);   // prefetched first pair

    #pragma unroll
    for (int rr = 0; rr < 2; ++rr) {
        {
            short8 b0 = wload(0, 2*rr+1, 0), b1 = wload(0, 2*rr+1, 1);
            gemm_q(pw0, pw1, bqkv[(2*rr)*16 + n16], 0);
            gemm_q(b0,  b1,  bqkv[(2*rr+1)*16 + n16], 16);
            short8 c0 = wload(1, 2*rr,   0), c1 = wload(1, 2*rr,   1);
            short8 d0 = wload(1, 2*rr+1, 0), d1 = wload(1, 2*rr+1, 1);
            gemm_k(c0, c1, bqkv[64 + (2*rr)*16 + n16],  0);
            gemm_k(d0, d1, bqkv[64 + (2*rr+1)*16 + n16], 16);
        }
        __syncthreads();
        // prefetch next phase's first pair AFTER the barrier: overlaps the
        // dot phase, drains at the NEXT barrier
        if (rr == 0) { pw0 = wload(0, 2, 0); pw1 = wload(0, 2, 1); }
        else         { pw0 = wload(2, 0, 0); pw1 = wload(2, 0, 1); }
        if (oin) {
            int swq = kqswz(t);
            uint4_ qa = *(const uint4_*)&qbuf2[t*KQS2 + ((0^swq)<<3)];
            uint4_ qb = *(const uint4_*)&qbuf2[t*KQS2 + ((1^swq)<<3)];
            uint4_ qc = *(const uint4_*)&qbuf2[t*KQS2 + ((2^swq)<<3)];
            uint4_ qd = *(const uint4_*)&qbuf2[t*KQS2 + ((3^swq)<<3)];
            #pragma unroll
            for (int n2 = 0; n2 < 9; ++n2) {
                int np = xpix + (n2/3 - 1)*XPW + (n2%3 - 1);
                int swk = kqswz(np);
                uint4_ ka = *(const uint4_*)&kbuf2[np*KQS2 + ((0^swk)<<3)];
                uint4_ kb = *(const uint4_*)&kbuf2[np*KQS2 + ((1^swk)<<3)];
                uint4_ kc = *(const uint4_*)&kbuf2[np*KQS2 + ((2^swk)<<3)];
                uint4_ kd = *(const uint4_*)&kbuf2[np*KQS2 + ((3^swk)<<3)];
                float s = dots[n2];
                #pragma unroll
                for (int j = 0; j < 4; ++j) s = dot2acc(qa[j], ka[j], s);
                #pragma unroll
                for (int j = 0; j < 4; ++j) s = dot2acc(qb[j], kb[j], s);
                #pragma unroll
                for (int j = 0; j < 4; ++j) s = dot2acc(qc[j], kc[j], s);
                #pragma unroll
                for (int j = 0; j < 4; ++j) s = dot2acc(qd[j], kd[j], s);
                dots[n2] = s;
            }
        }
        __syncthreads();
    }

    // ---- softmax (registers)
    float attn[9];
    if (oin) {
        float mx = -1e30f;
        #pragma unroll
        for (int n2 = 0; n2 < 9; ++n2) { dots[n2] *= 0.125f; mx = fmaxf(mx, dots[n2]); }
        float se = 0.f;
        #pragma unroll
        for (int n2 = 0; n2 < 9; ++n2) { attn[n2] = __expf(dots[n2] - mx); se += attn[n2]; }
        float inv = 1.f / se;
        #pragma unroll
        for (int n2 = 0; n2 < 9; ++n2) attn[n2] *= inv;
    }

    // ---- V: 4 rounds x 16 ch (vbuf is only [240][16]: the LDS shrink that
    // buys the 5th block/CU)
    #pragma unroll
    for (int q16 = 0; q16 < 4; ++q16) {
        gemm_v(pw0, pw1, bqkv[128 + q16*16 + n16]);
        __syncthreads();
        if (q16 < 3) { pw0 = wload(2, q16+1, 0); pw1 = wload(2, q16+1, 1); }
        if (t < NOP) {
            short8 s0, s1;
            if (oin) {
                float o1[16];
                uint4_ r0 = __builtin_bit_cast(uint4_, resi[q16*2]);
                uint4_ r1 = __builtin_bit_cast(uint4_, resi[q16*2 + 1]);
                #pragma unroll
                for (int j = 0; j < 4; ++j) {
                    o1[2*j]     = blo(r0[j]); o1[2*j + 1]     = bhi(r0[j]);
                    o1[8 + 2*j] = blo(r1[j]); o1[8 + 2*j + 1] = bhi(r1[j]);
                }
                #pragma unroll
                for (int n2 = 0; n2 < 9; ++n2) {
                    float a = attn[n2];
                    int np = xpix + (n2/3 - 1)*XPW + (n2%3 - 1);
                    int sw = (np ^ (np >> 2)) & 1;
                    uint4_ va = *(const uint4_*)&vbuf[np*VSS + ((0^sw)<<3)];
                    uint4_ vb = *(const uint4_*)&vbuf[np*VSS + ((1^sw)<<3)];
                    #pragma unroll
                    for (int j = 0; j < 4; ++j) {
                        o1[2*j]         += a * blo(va[j]);
                        o1[2*j + 1]     += a * bhi(va[j]);
                        o1[8 + 2*j]     += a * blo(vb[j]);
                        o1[8 + 2*j + 1] += a * bhi(vb[j]);
                    }
                }
                #pragma unroll
                for (int j = 0; j < 8; ++j) {
                    s0[j] = f2bs(o1[j]);
                    s1[j] = f2bs(o1[8 + j]);
                }
            } else {
                #pragma unroll
                for (int j = 0; j < 8; ++j) { s0[j] = 0; s1[j] = 0; }  // conv zero-pad
            }
            *(short8*)&o1b[o1_idx(t, q16*16)]     = s0;
            *(short8*)&o1b[o1_idx(t, q16*16 + 8)] = s1;
        }
        __syncthreads();
    }

    // ---- 3x3 conv 64->64 as one MFMA burst (K=576 tap-major), B from ws.
    // Weights loaded in-loop (round-5 prefetch rotation spilled: FETCH/WRITE
    // +45 MB symmetric -- reverted).
    float4_ acc[4][2];
    #pragma unroll
    for (int nt = 0; nt < 4; ++nt) {
        acc[nt][0] = (float4_){0.f,0.f,0.f,0.f};
        acc[nt][1] = (float4_){0.f,0.f,0.f,0.f};
    }
    const int mtc0 = w*2, mtc1 = w*2 + 1;
    for (int ks = 0; ks < 18; ++ks) {
        int tap = ks >> 1;
        int dy = tap/3 - 1, dx = tap%3 - 1;
        int cin0 = (ks & 1)*32 + quad*8;
        int pixA = (mtc0 + 1 + dy)*OPW + (n16 + 1 + dx);
        int pixB = (mtc1 + 1 + dy)*OPW + (n16 + 1 + dx);
        short8 a0 = *(const short8*)&o1b[o1_idx(pixA, cin0)];
        short8 a1 = *(const short8*)&o1b[o1_idx(pixB, cin0)];
        #pragma unroll
        for (int nt = 0; nt < 4; ++nt) {
            short8 bb = *(const short8*)&wsm[((nt*18 + ks) << 9) + lane*8];
            acc[nt][0] = __builtin_amdgcn_mfma_f32_16x16x32_bf16(a0, bb, acc[nt][0], 0, 0, 0);
            acc[nt][1] = __builtin_amdgcn_mfma_f32_16x16x32_bf16(a1, bb, acc[nt][1], 0, 0, 0);
        }
    }
    __syncthreads();   // tbuf overlaps vbuf/o1b: all conv reads must land

    // ---- epilogue: two 32-ch halves through one tbuf, coalesced stores
    #pragma unroll
    for (int half = 0; half < 2; ++half) {
        if (half) __syncthreads();     // stores of half0 must finish
        #pragma unroll
        for (int ntl = 0; ntl < 2; ++ntl) {
            int nt = half*2 + ntl;
            #pragma unroll
            for (int r = 0; r < 4; ++r) {
                tbuf[(mtc0*16 + quad*4 + r)*TSF + ntl*16 + n16] = fmaxf(acc[nt][0][r], 0.f);
                tbuf[(mtc1*16 + quad*4 + r)*TSF + ntl*16 + n16] = fmaxf(acc[nt][1][r], 0.f);
            }
        }
        __syncthreads();
        {
            int pl = t & 127, oh = t >> 7;
            int ty_ = pl >> 4, tx_ = pl & 15;
            float* op = out + (size_t)b*CHW + (size_t)(half*32 + oh*16)*HW
                        + (size_t)(gy0 + ty_)*WW + (gx0 + tx_);
            #pragma unroll
            for (int ii = 0; ii < 16; ++ii)
                op[(size_t)ii*HW] = tbuf[pl*TSF + oh*16 + ii];
        }
    }
}

extern "C" void kernel_launch(void* const* d_in, const int* in_sizes, int n_in,
                              void* d_out, int out_size, void* d_ws, size_t ws_size,
                              hipStream_t stream) {
    const float* x    = (const float*)d_in[0];
    const float* wqkv = (const float*)d_in[1];
    const float* bqkv = (const float*)d_in[2];
    const float* wmlp = (const float*)d_in[3];
    float* outp = (float*)d_out;

    short* wsq = (short*)d_ws;                      // 24576 B
    short* wsm = wsq + WSQ_SHORTS;                  // 73728 B  (total 98304 B)

    prep_pack<<<128, 256, 0, stream>>>(wqkv, wmlp, wsq, wsm);

    dim3 grid(WW/TW, HH/TH, 4);
    fused_mfma<<<grid, 256, 0, stream>>>(x, wsq, bqkv, wsm, outp);
}

// Round 7
// 254.794 us; speedup vs baseline: 1.2026x; 1.2026x over previous
//
#include <hip/hip_runtime.h>
#include <hip/hip_bf16.h>

typedef __attribute__((ext_vector_type(8))) short short8;
typedef __attribute__((ext_vector_type(4))) short short4_;
typedef __attribute__((ext_vector_type(4))) float float4_;
typedef __attribute__((ext_vector_type(4))) unsigned int uint4_;

#define CH 64
#define HH 256
#define WW 256
#define HW (HH*WW)
#define CHW (CH*HW)

#define TW 16
#define TH 8
#define XPW 20
#define XPH 12
#define NXP 240        // x/qkv halo set (halo 2)
#define OPW 18
#define OPH 10
#define NOP 180        // out1 set (halo 1)

#define XLS 72         // x LDS row stride (shorts). 144 B: consecutive pixels
                       // differ by 4 banks -> afr/resi/staging spread. Round-6
                       // evidence: XLS=64 (128 B = bank period) collapses all
                       // rows to bank 0 -> conflicts +43%. KEEP 72.
#define KQ2 40         // QK round stride (80 B = 5*16): b128 rows, bank starts
                       // step 20 mod 32 -> spread (round-4/5 verified)
#define VS  32         // vbuf stride (64 B rows) + granule swizzle
#define O1S 64         // o1b stride (128 B rows) + granule swizzle ^pix&7:
                       // conv reads/PV writes spread via per-lane pix
#define TSF 33         // tbuf row stride (floats)

// LDS regions (shorts):
//  xls   [0, 17280)
//  QK:   kbuf2 [0, 9600) = [240][40] ; qbuf2 [9600, 16800) = [180][40]
//  V:    vbuf  [0, 7680) = [240][32]sw ; o1b [7680, 19200) = [180][64]sw
//  epi:  tbA [0, 8448) ; tbB [8448, 16896)  (floats [128][33] each)
#define QB2_OFF 9600
#define O1_OFF  7680
#define SMEM_SHORTS 19200      // 38400 B -> 4 blocks/CU
// NOTE (round-6): occupancy is VGPR-capped at 4 waves/SIMD (VGPR=84, steps at
// 64/128) -> shrinking LDS below ~40KB buys NOTHING. 4 blocks/CU is the cap.

// ws layout: wsq bf16 [0,24576) ; wsm bf16 [24576, 98304)
#define WSQ_SHORTS 12288
#define WSM_SHORTS 36864

__device__ __forceinline__ float b2f(unsigned short u) {
    return __uint_as_float(((unsigned)u) << 16);
}
__device__ __forceinline__ float blo(unsigned u) {      // even channel of pair
    return __uint_as_float(u << 16);
}
__device__ __forceinline__ float bhi(unsigned u) {      // odd channel of pair
    return __uint_as_float(u & 0xffff0000u);
}
__device__ __forceinline__ short f2bs(float f) {
    __hip_bfloat16 h = __float2bfloat16(f);
    short s; __builtin_memcpy(&s, &h, 2); return s;
}
__device__ __forceinline__ unsigned pack2(float a, float b) {
    return (unsigned)(unsigned short)f2bs(a) |
           ((unsigned)(unsigned short)f2bs(b) << 16);
}

// xls swizzled index: channel c of halo pixel pix
__device__ __forceinline__ int xls_idx(int pix, int c) {
    int g = ((c >> 3) ^ ((pix >> 2) & 7));
    return pix * XLS + g * 8 + (c & 7);
}
// o1b swizzled index (granule = 16B block of 8 channels)
__device__ __forceinline__ int o1_idx(int pix, int c) {
    int g = (((c >> 3) ^ pix) & 7);
    return pix * O1S + g * 8 + (c & 7);
}
// vbuf swizzle key for pixel p
__device__ __forceinline__ int vswz(int p) {
    return (p ^ (p >> 2)) & 3;
}

#if defined(__has_builtin)
#if __has_builtin(__builtin_amdgcn_fdot2_f32_bf16)
#define HAS_BF16_DOT2 1
#endif
#endif
#ifdef HAS_BF16_DOT2
typedef __bf16 bf16x2 __attribute__((ext_vector_type(2)));
__device__ __forceinline__ float dot2acc(unsigned a, unsigned b, float acc) {
    return __builtin_amdgcn_fdot2_f32_bf16(__builtin_bit_cast(bf16x2, a),
                                           __builtin_bit_cast(bf16x2, b),
                                           acc, false);
}
#else
__device__ __forceinline__ float dot2acc(unsigned a, unsigned b, float acc) {
    acc += blo(a) * blo(b);
    acc += bhi(a) * bhi(b);
    return acc;
}
#endif

// ---- prep: pack wqkv/wmlp to bf16 in exact B-fragment order -----------------
__global__ void prep_pack(const float* __restrict__ wqkv,
                          const float* __restrict__ wmlp,
                          short* __restrict__ wsq, short* __restrict__ wsm) {
    int idx = blockIdx.x * blockDim.x + threadIdx.x;
    int stride = gridDim.x * blockDim.x;
    for (int e = idx; e < WSQ_SHORTS; e += stride) {
        int j = e & 7, lane = (e >> 3) & 63;
        int ks = (e >> 9) & 1, q16 = (e >> 10) & 3, sec = e >> 12;
        int row = sec*64 + q16*16 + (lane & 15);
        int kk  = ks*32 + (lane >> 4)*8 + j;
        wsq[e] = f2bs(wqkv[(size_t)row*64 + kk]);
    }
    for (int e = idx; e < WSM_SHORTS; e += stride) {
        int j = e & 7, lane = (e >> 3) & 63;
        int rest = e >> 9;            // 0..71
        int nt = rest / 18, ks = rest % 18;
        int o   = nt*16 + (lane & 15);
        int cin = (ks & 1)*32 + (lane >> 4)*8 + j;
        int tap = ks >> 1;
        wsm[e] = f2bs(wmlp[(size_t)o*576 + cin*9 + tap]);
    }
}

// ---- fused kernel -----------------------------------------------------------
// __launch_bounds__(256,3): (256,4) pinned the allocator at the 64-VGPR step
// and spilled (+250 MB HBM, round-1 evidence). Round-5's conv-weight prefetch
// (cw[4]+nw[4], +64 live VGPRs across the conv loop) also spilled (FETCH/WRITE
// +45 MB symmetric) -> REMOVED this round. Everything else = round-5 layout.
__global__ __launch_bounds__(256, 3) void fused_mfma(
    const float* __restrict__ x, const short* __restrict__ wsq,
    const float* __restrict__ bqkv, const short* __restrict__ wsm,
    float* __restrict__ out)
{
    __shared__ __align__(16) short smem[SMEM_SHORTS];
    short* xls   = smem;                             // phase X only (swizzled)
    short* kbuf2 = smem;                             // [240][40] QK rounds
    short* qbuf2 = smem + QB2_OFF;                   // [180][40] QK rounds
    short* vbuf  = smem;                             // [240][32]sw V rounds
    short* o1b   = smem + O1_OFF;                    // [180][64]sw V/conv
    float* tbA   = (float*)smem;                     // [128][33] epilogue
    float* tbB   = (float*)smem + 4224;              // [128][33] epilogue

    const int t    = threadIdx.x;
    const int w    = t >> 6;
    const int lane = t & 63;
    const int n16  = lane & 15;
    const int quad = lane >> 4;

    // XCD-chunk swizzle (round-2 verified: FETCH 260->58 MB): XCD k owns a
    // contiguous chunk of tiles -> halo reads and out half-lines share one
    // L2. 2048 % 8 == 0 -> bijective.
    const int d   = blockIdx.x + (blockIdx.y << 4) + (blockIdx.z << 9);
    const int nn  = ((d & 7) << 8) | (d >> 3);
    const int b   = nn >> 9;
    const int rem = nn & 511;
    const int gy0 = (rem >> 4) * TH;
    const int gx0 = (rem & 15) * TW;
    const float* xb = x + (size_t)b * CHW;

    // NOTE: all 4 waves process exactly 4 M-tiles (16th tile is a clamped
    // dummy) so every register-array index is compile-time static.
    // Dynamic-bound loops over register arrays caused scratch spills.

    // ---- phase X: stage x halo into LDS bf16. Channel-PAIR packed b32
    // writes + granule swizzle (round-4 verified: conflicts 1.87e7 -> 6.7e6;
    // residual ~3.3k cyc/block is structural at b32 width, ~2%: accept).
    for (int slot = t; slot < 32*12*6; slot += 256) {
        int s6 = slot % 6, y = (slot / 6) % 12, c2 = slot / 72;
        int c  = c2 * 2;
        int gy = gy0 - 2 + y;
        int gxb = gx0 - 4 + s6*4;
        float v0[4], v1[4];
        bool gyok = (unsigned)gy < HH;
        if (gyok && gxb >= 0 && gxb + 3 < WW) {
            float4_ f0 = *(const float4_*)(xb + (size_t)c*HW + gy*WW + gxb);
            float4_ f1 = *(const float4_*)(xb + (size_t)(c+1)*HW + gy*WW + gxb);
            #pragma unroll
            for (int i = 0; i < 4; ++i) { v0[i] = f0[i]; v1[i] = f1[i]; }
        } else {
            #pragma unroll
            for (int i = 0; i < 4; ++i) {
                int gx = gxb + i;
                bool ok = gyok && (unsigned)gx < WW;
                v0[i] = ok ? xb[(size_t)c*HW + gy*WW + gx] : 0.f;
                v1[i] = ok ? xb[(size_t)(c+1)*HW + gy*WW + gx] : 0.f;
            }
        }
        #pragma unroll
        for (int i = 0; i < 4; ++i) {
            int pxc = s6*4 + i - 2;
            if ((unsigned)pxc < XPW)
                *(unsigned*)&xls[xls_idx(y*XPW + pxc, c)] = pack2(v0[i], v1[i]);
        }
    }
    __syncthreads();

    // OOB bitmask: bit(i*4+r) -> halo pixel (w*4+i)*16 + quad*4 + r
    unsigned okbits = 0;
    #pragma unroll
    for (int i = 0; i < 4; ++i)
        #pragma unroll
        for (int r = 0; r < 4; ++r) {
            int p = (w*4 + i)*16 + quad*4 + r;
            if (p < NXP) {
                int gy = gy0 - 2 + p / XPW, gx = gx0 - 2 + p % XPW;
                if (((unsigned)gy < HH) && ((unsigned)gx < WW))
                    okbits |= 1u << (i*4 + r);
            }
        }

    // ---- A-frags (swizzled reads, static-indexed) + residual capture
    short8 afr[4][2];
    #pragma unroll
    for (int i = 0; i < 4; ++i) {
        int p = (w*4 + i)*16 + n16;
        int pr = (p < NXP) ? p : 0;        // clamped dummy for wave3/i3
        #pragma unroll
        for (int ks = 0; ks < 2; ++ks)
            afr[i][ks] = *(const short8*)&xls[xls_idx(pr, ks*32 + quad*8)];
    }
    // per-thread attention pixel
    const int op_py = t / OPW, op_px = t % OPW;
    const int ogy = gy0 - 1 + op_py, ogx = gx0 - 1 + op_px;
    const bool oin = (t < NOP) && ((unsigned)ogy < HH) && ((unsigned)ogx < WW);
    const int xpix = (op_py + 1)*XPW + (op_px + 1);
    short8 resi[8];
    if (t < NOP) {
        #pragma unroll
        for (int g = 0; g < 8; ++g)
            resi[g] = *(const short8*)&xls[xls_idx(xpix, g*8)];
    }
    __syncthreads();   // xls dead; k/q regions may now be written

    // B-fragment loader (global, L2-resident 24 KB)
    auto wload = [&](int sec, int q16, int ks) -> short8 {
        return *(const short8*)&wsq[(((sec*4 + q16)*2 + ks) << 9) + lane*8];
    };
    // gemm 16 out-ch into kbuf2 (linear stride KQ2), OOB rows zeroed
    auto gemm_k = [&](short8 b0, short8 b1, float bias, int coff) {
        #pragma unroll
        for (int i = 0; i < 4; ++i) {
            float4_ c = {0.f, 0.f, 0.f, 0.f};
            c = __builtin_amdgcn_mfma_f32_16x16x32_bf16(afr[i][0], b0, c, 0, 0, 0);
            c = __builtin_amdgcn_mfma_f32_16x16x32_bf16(afr[i][1], b1, c, 0, 0, 0);
            #pragma unroll
            for (int r = 0; r < 4; ++r) {
                int p = (w*4 + i)*16 + quad*4 + r;
                bool ok = (okbits >> (i*4 + r)) & 1u;
                if (p < NXP)
                    kbuf2[p*KQ2 + coff + n16] = ok ? f2bs(c[r] + bias) : (short)0;
            }
        }
    };
    // gemm 16 out-ch into vbuf (granule-swizzled stride VS)
    auto gemm_v = [&](short8 b0, short8 b1, float bias, int coff) {
        #pragma unroll
        for (int i = 0; i < 4; ++i) {
            float4_ c = {0.f, 0.f, 0.f, 0.f};
            c = __builtin_amdgcn_mfma_f32_16x16x32_bf16(afr[i][0], b0, c, 0, 0, 0);
            c = __builtin_amdgcn_mfma_f32_16x16x32_bf16(afr[i][1], b1, c, 0, 0, 0);
            #pragma unroll
            for (int r = 0; r < 4; ++r) {
                int p = (w*4 + i)*16 + quad*4 + r;
                bool ok = (okbits >> (i*4 + r)) & 1u;
                if (p < NXP) {
                    int cc = coff + n16;
                    int idx = p*VS + ((((cc >> 3) ^ vswz(p)) & 3) << 3) + (cc & 7);
                    vbuf[idx] = ok ? f2bs(c[r] + bias) : (short)0;
                }
            }
        }
    };
    // gemm 16 out-ch of q, stored interior-compressed (180 rows)
    auto gemm_q = [&](short8 b0, short8 b1, float bias, int coff) {
        #pragma unroll
        for (int i = 0; i < 4; ++i) {
            float4_ c = {0.f, 0.f, 0.f, 0.f};
            c = __builtin_amdgcn_mfma_f32_16x16x32_bf16(afr[i][0], b0, c, 0, 0, 0);
            c = __builtin_amdgcn_mfma_f32_16x16x32_bf16(afr[i][1], b1, c, 0, 0, 0);
            #pragma unroll
            for (int r = 0; r < 4; ++r) {
                int p = (w*4 + i)*16 + quad*4 + r;
                int py = p / XPW, px = p % XPW;
                if ((unsigned)(py - 1) < (unsigned)OPH &&
                    (unsigned)(px - 1) < (unsigned)OPW) {
                    int op = (py - 1)*OPW + (px - 1);
                    qbuf2[op*KQ2 + coff + n16] = f2bs(c[r] + bias);
                }
            }
        }
    };

    // ---- QK: 2 rounds x 32 channels
    float dots[9];
    #pragma unroll
    for (int n2 = 0; n2 < 9; ++n2) dots[n2] = 0.f;

    short8 pw0 = wload(0,0,0), pw1 = wload(0,0,1);   // prefetched first pair

    #pragma unroll
    for (int rr = 0; rr < 2; ++rr) {
        {
            short8 b0 = wload(0, 2*rr+1, 0), b1 = wload(0, 2*rr+1, 1);
            gemm_q(pw0, pw1, bqkv[(2*rr)*16 + n16], 0);
            gemm_q(b0,  b1,  bqkv[(2*rr+1)*16 + n16], 16);
            short8 c0 = wload(1, 2*rr,   0), c1 = wload(1, 2*rr,   1);
            short8 d0 = wload(1, 2*rr+1, 0), d1 = wload(1, 2*rr+1, 1);
            gemm_k(c0, c1, bqkv[64 + (2*rr)*16 + n16],  0);
            gemm_k(d0, d1, bqkv[64 + (2*rr+1)*16 + n16], 16);
        }
        __syncthreads();
        // prefetch next phase's first pair AFTER the barrier: overlaps the
        // dot phase, drains at the NEXT barrier (compiler emits vmcnt(0) at
        // every s_barrier, so pre-barrier issues are useless)
        if (rr == 0) { pw0 = wload(0, 2, 0); pw1 = wload(0, 2, 1); }
        else         { pw0 = wload(2, 0, 0); pw1 = wload(2, 0, 1); }
        if (oin) {
            uint4_ qa = *(const uint4_*)&qbuf2[t*KQ2];
            uint4_ qb = *(const uint4_*)&qbuf2[t*KQ2 + 8];
            uint4_ qc = *(const uint4_*)&qbuf2[t*KQ2 + 16];
            uint4_ qd = *(const uint4_*)&qbuf2[t*KQ2 + 24];
            #pragma unroll
            for (int n2 = 0; n2 < 9; ++n2) {
                int np = xpix + (n2/3 - 1)*XPW + (n2%3 - 1);
                uint4_ ka = *(const uint4_*)&kbuf2[np*KQ2];
                uint4_ kb = *(const uint4_*)&kbuf2[np*KQ2 + 8];
                uint4_ kc = *(const uint4_*)&kbuf2[np*KQ2 + 16];
                uint4_ kd = *(const uint4_*)&kbuf2[np*KQ2 + 24];
                float s = dots[n2];
                #pragma unroll
                for (int j = 0; j < 4; ++j) s = dot2acc(qa[j], ka[j], s);
                #pragma unroll
                for (int j = 0; j < 4; ++j) s = dot2acc(qb[j], kb[j], s);
                #pragma unroll
                for (int j = 0; j < 4; ++j) s = dot2acc(qc[j], kc[j], s);
                #pragma unroll
                for (int j = 0; j < 4; ++j) s = dot2acc(qd[j], kd[j], s);
                dots[n2] = s;
            }
        }
        __syncthreads();
    }

    // ---- softmax (registers)
    float attn[9];
    if (oin) {
        float mx = -1e30f;
        #pragma unroll
        for (int n2 = 0; n2 < 9; ++n2) { dots[n2] *= 0.125f; mx = fmaxf(mx, dots[n2]); }
        float se = 0.f;
        #pragma unroll
        for (int n2 = 0; n2 < 9; ++n2) { attn[n2] = __expf(dots[n2] - mx); se += attn[n2]; }
        float inv = 1.f / se;
        #pragma unroll
        for (int n2 = 0; n2 < 9; ++n2) attn[n2] *= inv;
    }

    // ---- V: 2 rounds x 32 channels
    #pragma unroll
    for (int rr2 = 0; rr2 < 2; ++rr2) {
        {
            short8 b2 = wload(2, 2*rr2+1, 0), b3 = wload(2, 2*rr2+1, 1);
            gemm_v(pw0, pw1, bqkv[128 + (2*rr2)*16 + n16], 0);
            gemm_v(b2,  b3,  bqkv[128 + (2*rr2+1)*16 + n16], 16);
        }
        __syncthreads();
        if (rr2 == 0) { pw0 = wload(2, 2, 0); pw1 = wload(2, 2, 1); }
        if (t < NOP) {
            #pragma unroll
            for (int h2 = 0; h2 < 2; ++h2) {
                const int kg = rr2*2 + h2;           // 16-ch group 0..3
                short8 s0, s1;
                if (oin) {
                    float o1[16];
                    uint4_ r0 = __builtin_bit_cast(uint4_, resi[kg*2]);
                    uint4_ r1 = __builtin_bit_cast(uint4_, resi[kg*2 + 1]);
                    #pragma unroll
                    for (int j = 0; j < 4; ++j) {
                        o1[2*j]     = blo(r0[j]); o1[2*j + 1]     = bhi(r0[j]);
                        o1[8 + 2*j] = blo(r1[j]); o1[8 + 2*j + 1] = bhi(r1[j]);
                    }
                    #pragma unroll
                    for (int n2 = 0; n2 < 9; ++n2) {
                        float a = attn[n2];
                        int np = xpix + (n2/3 - 1)*XPW + (n2%3 - 1);
                        int sw = vswz(np);
                        uint4_ va = *(const uint4_*)&vbuf[np*VS + (((h2*2)   ^ sw) << 3)];
                        uint4_ vb = *(const uint4_*)&vbuf[np*VS + (((h2*2+1) ^ sw) << 3)];
                        #pragma unroll
                        for (int j = 0; j < 4; ++j) {
                            o1[2*j]         += a * blo(va[j]);
                            o1[2*j + 1]     += a * bhi(va[j]);
                            o1[8 + 2*j]     += a * blo(vb[j]);
                            o1[8 + 2*j + 1] += a * bhi(vb[j]);
                        }
                    }
                    #pragma unroll
                    for (int j = 0; j < 8; ++j) {
                        s0[j] = f2bs(o1[j]);
                        s1[j] = f2bs(o1[8 + j]);
                    }
                } else {
                    #pragma unroll
                    for (int j = 0; j < 8; ++j) { s0[j] = 0; s1[j] = 0; }  // conv zero-pad
                }
                *(short8*)&o1b[o1_idx(t, kg*16)]     = s0;
                *(short8*)&o1b[o1_idx(t, kg*16 + 8)] = s1;
            }
        }
        __syncthreads();
    }

    // ---- 3x3 conv 64->64 as one MFMA burst (K=576 tap-major), B from ws.
    // Weights loaded IN-LOOP: the cw[4]/nw[4] prefetch rotation (round 5)
    // added 64 live VGPRs across this loop and spilled (FETCH/WRITE +45 MB).
    float4_ acc[4][2];
    #pragma unroll
    for (int nt = 0; nt < 4; ++nt) {
        acc[nt][0] = (float4_){0.f,0.f,0.f,0.f};
        acc[nt][1] = (float4_){0.f,0.f,0.f,0.f};
    }
    const int mtc0 = w*2, mtc1 = w*2 + 1;
    for (int ks = 0; ks < 18; ++ks) {
        int tap = ks >> 1;
        int dy = tap/3 - 1, dx = tap%3 - 1;
        int cin0 = (ks & 1)*32 + quad*8;
        int pixA = (mtc0 + 1 + dy)*OPW + (n16 + 1 + dx);
        int pixB = (mtc1 + 1 + dy)*OPW + (n16 + 1 + dx);
        short8 a0 = *(const short8*)&o1b[o1_idx(pixA, cin0)];
        short8 a1 = *(const short8*)&o1b[o1_idx(pixB, cin0)];
        #pragma unroll
        for (int nt = 0; nt < 4; ++nt) {
            short8 bb = *(const short8*)&wsm[((nt*18 + ks) << 9) + lane*8];
            acc[nt][0] = __builtin_amdgcn_mfma_f32_16x16x32_bf16(a0, bb, acc[nt][0], 0, 0, 0);
            acc[nt][1] = __builtin_amdgcn_mfma_f32_16x16x32_bf16(a1, bb, acc[nt][1], 0, 0, 0);
        }
    }
    __syncthreads();   // tbA/tbB overlap vbuf/o1b: all conv reads must land

    // ---- epilogue: two 32-ch halves through SEPARATE tbufs
    #pragma unroll
    for (int ntl = 0; ntl < 2; ++ntl)
        #pragma unroll
        for (int r = 0; r < 4; ++r) {
            tbA[(mtc0*16 + quad*4 + r)*TSF + ntl*16 + n16] = fmaxf(acc[ntl][0][r], 0.f);
            tbA[(mtc1*16 + quad*4 + r)*TSF + ntl*16 + n16] = fmaxf(acc[ntl][1][r], 0.f);
        }
    __syncthreads();
    {
        int pl = t & 127, oh = t >> 7;
        int ty_ = pl >> 4, tx_ = pl & 15;
        float* op = out + (size_t)b*CHW + (size_t)(oh*16)*HW
                    + (size_t)(gy0 + ty_)*WW + (gx0 + tx_);
        #pragma unroll
        for (int ii = 0; ii < 16; ++ii)
            op[(size_t)ii*HW] = tbA[pl*TSF + oh*16 + ii];
    }
    #pragma unroll
    for (int ntl = 0; ntl < 2; ++ntl)
        #pragma unroll
        for (int r = 0; r < 4; ++r) {
            tbB[(mtc0*16 + quad*4 + r)*TSF + ntl*16 + n16] = fmaxf(acc[2+ntl][0][r], 0.f);
            tbB[(mtc1*16 + quad*4 + r)*TSF + ntl*16 + n16] = fmaxf(acc[2+ntl][1][r], 0.f);
        }
    __syncthreads();
    {
        int pl = t & 127, oh = t >> 7;
        int ty_ = pl >> 4, tx_ = pl & 15;
        float* op = out + (size_t)b*CHW + (size_t)(32 + oh*16)*HW
                    + (size_t)(gy0 + ty_)*WW + (gx0 + tx_);
        #pragma unroll
        for (int ii = 0; ii < 16; ++ii)
            op[(size_t)ii*HW] = tbB[pl*TSF + oh*16 + ii];
    }
}

extern "C" void kernel_launch(void* const* d_in, const int* in_sizes, int n_in,
                              void* d_out, int out_size, void* d_ws, size_t ws_size,
                              hipStream_t stream) {
    const float* x    = (const float*)d_in[0];
    const float* wqkv = (const float*)d_in[1];
    const float* bqkv = (const float*)d_in[2];
    const float* wmlp = (const float*)d_in[3];
    float* outp = (float*)d_out;

    short* wsq = (short*)d_ws;                      // 24576 B
    short* wsm = wsq + WSQ_SHORTS;                  // 73728 B  (total 98304 B)

    prep_pack<<<128, 256, 0, stream>>>(wqkv, wmlp, wsq, wsm);

    dim3 grid(WW/TW, HH/TH, 4);
    fused_mfma<<<grid, 256, 0, stream>>>(x, wsq, bqkv, wsm, outp);
}

// Round 8
// 235.592 us; speedup vs baseline: 1.3007x; 1.0815x over previous
//
#include <hip/hip_runtime.h>
#include <hip/hip_bf16.h>

typedef __attribute__((ext_vector_type(8))) short short8;
typedef __attribute__((ext_vector_type(4))) short short4_;
typedef __attribute__((ext_vector_type(4))) float float4_;
typedef __attribute__((ext_vector_type(4))) unsigned int uint4_;

#define CH 64
#define HH 256
#define WW 256
#define HW (HH*WW)
#define CHW (CH*HW)

#define TW 16
#define TH 8
#define XPW 20
#define XPH 12
#define NXP 240        // x/qkv halo set (halo 2)
#define OPW 18
#define OPH 10
#define NOP 180        // out1 set (halo 1)

#define XLS 72         // x LDS row stride (shorts). 144 B: consecutive pixels
                       // differ by 4 banks. Round-6 evidence: 64 (=bank
                       // period) collapses rows to bank 0, conflicts +43%.
#define KQ2 40         // QK round stride (80 B): row bank-starts step 20%32
                       // -> full coverage; b128 reads & b64 stores minimal
#define VS  32         // vbuf stride (64 B rows) + granule swizzle
#define O1S 64         // o1b stride (128 B rows) + granule swizzle ^pix&7
#define TSF 33         // tbuf row stride (floats)

// LDS regions (shorts):
//  xls   [0, 17280)
//  QK:   kbuf2 [0, 9600) = [240][40] ; qbuf2 [9600, 16800) = [180][40]
//  V:    vbuf  [0, 7680) = [240][32]sw ; o1b [7680, 19200) = [180][64]sw
//  epi:  tbA [0, 8448) ; tbB [8448, 16896)  (floats [128][33] each)
#define QB2_OFF 9600
#define O1_OFF  7680
#define SMEM_SHORTS 19200      // 38400 B -> 4 blocks/CU
// Occupancy is VGPR-capped at 4 waves/SIMD (VGPR=84, halving steps at
// 64/128, round-6 evidence) -> LDS below ~40KB buys nothing. 4 blocks is
// the cap; the lever is per-phase issue count + dependency latency.

// ws layout: wsq bf16 [0,24576) ; wsm bf16 [24576, 98304)
#define WSQ_SHORTS 12288
#define WSM_SHORTS 36864

__device__ __forceinline__ float blo(unsigned u) {      // even channel of pair
    return __uint_as_float(u << 16);
}
__device__ __forceinline__ float bhi(unsigned u) {      // odd channel of pair
    return __uint_as_float(u & 0xffff0000u);
}
__device__ __forceinline__ short f2bs(float f) {
    __hip_bfloat16 h = __float2bfloat16(f);
    short s; __builtin_memcpy(&s, &h, 2); return s;
}
__device__ __forceinline__ unsigned pack2(float a, float b) {
    return (unsigned)(unsigned short)f2bs(a) |
           ((unsigned)(unsigned short)f2bs(b) << 16);
}

// xls swizzled index: channel c of halo pixel pix
__device__ __forceinline__ int xls_idx(int pix, int c) {
    int g = ((c >> 3) ^ ((pix >> 2) & 7));
    return pix * XLS + g * 8 + (c & 7);
}
// o1b swizzled index (granule = 16B block of 8 channels)
__device__ __forceinline__ int o1_idx(int pix, int c) {
    int g = (((c >> 3) ^ pix) & 7);
    return pix * O1S + g * 8 + (c & 7);
}
// vbuf swizzle key for pixel p
__device__ __forceinline__ int vswz(int p) {
    return (p ^ (p >> 2)) & 3;
}

#if defined(__has_builtin)
#if __has_builtin(__builtin_amdgcn_fdot2_f32_bf16)
#define HAS_BF16_DOT2 1
#endif
#endif
#ifdef HAS_BF16_DOT2
typedef __bf16 bf16x2 __attribute__((ext_vector_type(2)));
__device__ __forceinline__ float dot2acc(unsigned a, unsigned b, float acc) {
    return __builtin_amdgcn_fdot2_f32_bf16(__builtin_bit_cast(bf16x2, a),
                                           __builtin_bit_cast(bf16x2, b),
                                           acc, false);
}
#else
__device__ __forceinline__ float dot2acc(unsigned a, unsigned b, float acc) {
    acc += blo(a) * blo(b);
    acc += bhi(a) * bhi(b);
    return acc;
}
#endif

// ---- prep: pack wqkv/wmlp to bf16 in exact fragment order -------------------
// NOTE: for mfma_f32_16x16x32_bf16, A and B fragments are symmetric (lane&15
// selects the non-K index, (lane>>4)*8+j the K index), so this pack order
// serves wsq both as B (x-as-A, rounds 0-7) and as A (weights-first, this
// round's swapped-operand form).
__global__ void prep_pack(const float* __restrict__ wqkv,
                          const float* __restrict__ wmlp,
                          short* __restrict__ wsq, short* __restrict__ wsm) {
    int idx = blockIdx.x * blockDim.x + threadIdx.x;
    int stride = gridDim.x * blockDim.x;
    for (int e = idx; e < WSQ_SHORTS; e += stride) {
        int j = e & 7, lane = (e >> 3) & 63;
        int ks = (e >> 9) & 1, q16 = (e >> 10) & 3, sec = e >> 12;
        int row = sec*64 + q16*16 + (lane & 15);
        int kk  = ks*32 + (lane >> 4)*8 + j;
        wsq[e] = f2bs(wqkv[(size_t)row*64 + kk]);
    }
    for (int e = idx; e < WSM_SHORTS; e += stride) {
        int j = e & 7, lane = (e >> 3) & 63;
        int rest = e >> 9;            // 0..71
        int nt = rest / 18, ks = rest % 18;
        int o   = nt*16 + (lane & 15);
        int cin = (ks & 1)*32 + (lane >> 4)*8 + j;
        int tap = ks >> 1;
        wsm[e] = f2bs(wmlp[(size_t)o*576 + cin*9 + tap]);
    }
}

// ---- fused kernel -----------------------------------------------------------
// __launch_bounds__(256,3): (256,4) pinned the allocator at the 64-VGPR step
// and spilled (+250 MB HBM, round-1 evidence).
// Round-8 change: SWAPPED MFMA OPERANDS in all qkv gemms — mfma(w, x, c)
// gives D[outch][pixel]: each lane holds 4 CONSECUTIVE CHANNELS of one pixel
// (row=quad*4+r, col=n16=pixel) -> one ds_write_b64 per tile instead of four
// ds_write_b16 (208 -> 52 LDS store issues/thread across the 13 gemms), and
// the OOB test becomes per-tile instead of per-element.
__global__ __launch_bounds__(256, 3) void fused_mfma(
    const float* __restrict__ x, const short* __restrict__ wsq,
    const float* __restrict__ bqkv, const short* __restrict__ wsm,
    float* __restrict__ out)
{
    __shared__ __align__(16) short smem[SMEM_SHORTS];
    short* xls   = smem;                             // phase X only (swizzled)
    short* kbuf2 = smem;                             // [240][40] QK rounds
    short* qbuf2 = smem + QB2_OFF;                   // [180][40] QK rounds
    short* vbuf  = smem;                             // [240][32]sw V rounds
    short* o1b   = smem + O1_OFF;                    // [180][64]sw V/conv
    float* tbA   = (float*)smem;                     // [128][33] epilogue
    float* tbB   = (float*)smem + 4224;              // [128][33] epilogue

    const int t    = threadIdx.x;
    const int w    = t >> 6;
    const int lane = t & 63;
    const int n16  = lane & 15;
    const int quad = lane >> 4;

    // XCD-chunk swizzle (round-2 verified: FETCH 260->58 MB): XCD k owns a
    // contiguous chunk of tiles. 2048 % 8 == 0 -> bijective.
    const int d   = blockIdx.x + (blockIdx.y << 4) + (blockIdx.z << 9);
    const int nn  = ((d & 7) << 8) | (d >> 3);
    const int b   = nn >> 9;
    const int rem = nn & 511;
    const int gy0 = (rem >> 4) * TH;
    const int gx0 = (rem & 15) * TW;
    const float* xb = x + (size_t)b * CHW;

    // ---- phase X: stage x halo into LDS bf16. Channel-PAIR packed b32
    // writes + granule swizzle (round-4 verified: conflicts 1.87e7 -> 6.7e6;
    // residual ~3.3k cyc/block is structural at b32 width, ~2%: accept).
    for (int slot = t; slot < 32*12*6; slot += 256) {
        int s6 = slot % 6, y = (slot / 6) % 12, c2 = slot / 72;
        int c  = c2 * 2;
        int gy = gy0 - 2 + y;
        int gxb = gx0 - 4 + s6*4;
        float v0[4], v1[4];
        bool gyok = (unsigned)gy < HH;
        if (gyok && gxb >= 0 && gxb + 3 < WW) {
            float4_ f0 = *(const float4_*)(xb + (size_t)c*HW + gy*WW + gxb);
            float4_ f1 = *(const float4_*)(xb + (size_t)(c+1)*HW + gy*WW + gxb);
            #pragma unroll
            for (int i = 0; i < 4; ++i) { v0[i] = f0[i]; v1[i] = f1[i]; }
        } else {
            #pragma unroll
            for (int i = 0; i < 4; ++i) {
                int gx = gxb + i;
                bool ok = gyok && (unsigned)gx < WW;
                v0[i] = ok ? xb[(size_t)c*HW + gy*WW + gx] : 0.f;
                v1[i] = ok ? xb[(size_t)(c+1)*HW + gy*WW + gx] : 0.f;
            }
        }
        #pragma unroll
        for (int i = 0; i < 4; ++i) {
            int pxc = s6*4 + i - 2;
            if ((unsigned)pxc < XPW)
                *(unsigned*)&xls[xls_idx(y*XPW + pxc, c)] = pack2(v0[i], v1[i]);
        }
    }
    __syncthreads();

    // per-tile OOB mask: bit i -> pixel (w*4+i)*16 + n16 (uniform in quad/r
    // under the swapped-operand C layout)
    unsigned okb = 0;
    #pragma unroll
    for (int i = 0; i < 4; ++i) {
        int p = (w*4 + i)*16 + n16;
        if (p < NXP) {
            int gy = gy0 - 2 + p / XPW, gx = gx0 - 2 + p % XPW;
            if (((unsigned)gy < HH) && ((unsigned)gx < WW))
                okb |= 1u << i;
        }
    }

    // ---- A-frags (swizzled reads, static-indexed) + residual capture
    short8 afr[4][2];
    #pragma unroll
    for (int i = 0; i < 4; ++i) {
        int p = (w*4 + i)*16 + n16;
        int pr = (p < NXP) ? p : 0;        // clamped dummy for wave3/i3
        #pragma unroll
        for (int ks = 0; ks < 2; ++ks)
            afr[i][ks] = *(const short8*)&xls[xls_idx(pr, ks*32 + quad*8)];
    }
    // per-thread attention pixel
    const int op_py = t / OPW, op_px = t % OPW;
    const int ogy = gy0 - 1 + op_py, ogx = gx0 - 1 + op_px;
    const bool oin = (t < NOP) && ((unsigned)ogy < HH) && ((unsigned)ogx < WW);
    const int xpix = (op_py + 1)*XPW + (op_px + 1);
    short8 resi[8];
    if (t < NOP) {
        #pragma unroll
        for (int g = 0; g < 8; ++g)
            resi[g] = *(const short8*)&xls[xls_idx(xpix, g*8)];
    }
    __syncthreads();   // xls dead; k/q regions may now be written

    // B-fragment loader (global, L2-resident 24 KB)
    auto wload = [&](int sec, int q16, int ks) -> short8 {
        return *(const short8*)&wsq[(((sec*4 + q16)*2 + ks) << 9) + lane*8];
    };
    // 4 biases for channels base+quad*4+{0..3}
    auto bload = [&](int base) -> float4_ {
        return *(const float4_*)&bqkv[base + quad*4];
    };
    // gemm 16 out-ch, swapped operands: D[ch=quad*4+r][pix=n16]; one b64
    // store of 4 consecutive channels per tile
    auto gemm_k = [&](short8 w0, short8 w1, float4_ b4, int coff) {
        #pragma unroll
        for (int i = 0; i < 4; ++i) {
            int p = (w*4 + i)*16 + n16;
            float4_ c = {0.f, 0.f, 0.f, 0.f};
            c = __builtin_amdgcn_mfma_f32_16x16x32_bf16(w0, afr[i][0], c, 0, 0, 0);
            c = __builtin_amdgcn_mfma_f32_16x16x32_bf16(w1, afr[i][1], c, 0, 0, 0);
            if (p < NXP) {
                bool ok = (okb >> i) & 1u;
                short4_ s;
                #pragma unroll
                for (int r = 0; r < 4; ++r) s[r] = ok ? f2bs(c[r] + b4[r]) : (short)0;
                *(short4_*)&kbuf2[p*KQ2 + coff + quad*4] = s;
            }
        }
    };
    auto gemm_v = [&](short8 w0, short8 w1, float4_ b4, int coff) {
        #pragma unroll
        for (int i = 0; i < 4; ++i) {
            int p = (w*4 + i)*16 + n16;
            float4_ c = {0.f, 0.f, 0.f, 0.f};
            c = __builtin_amdgcn_mfma_f32_16x16x32_bf16(w0, afr[i][0], c, 0, 0, 0);
            c = __builtin_amdgcn_mfma_f32_16x16x32_bf16(w1, afr[i][1], c, 0, 0, 0);
            if (p < NXP) {
                bool ok = (okb >> i) & 1u;
                short4_ s;
                #pragma unroll
                for (int r = 0; r < 4; ++r) s[r] = ok ? f2bs(c[r] + b4[r]) : (short)0;
                int cc = coff + quad*4;
                int idx = p*VS + ((((cc >> 3) ^ vswz(p)) & 3) << 3) + (cc & 7);
                *(short4_*)&vbuf[idx] = s;
            }
        }
    };
    auto gemm_q = [&](short8 w0, short8 w1, float4_ b4, int coff) {
        #pragma unroll
        for (int i = 0; i < 4; ++i) {
            int p = (w*4 + i)*16 + n16;
            float4_ c = {0.f, 0.f, 0.f, 0.f};
            c = __builtin_amdgcn_mfma_f32_16x16x32_bf16(w0, afr[i][0], c, 0, 0, 0);
            c = __builtin_amdgcn_mfma_f32_16x16x32_bf16(w1, afr[i][1], c, 0, 0, 0);
            int py = p / XPW, px = p % XPW;
            if ((unsigned)(py - 1) < (unsigned)OPH &&
                (unsigned)(px - 1) < (unsigned)OPW) {
                int op = (py - 1)*OPW + (px - 1);
                short4_ s;
                #pragma unroll
                for (int r = 0; r < 4; ++r) s[r] = f2bs(c[r] + b4[r]);
                *(short4_*)&qbuf2[op*KQ2 + coff + quad*4] = s;
            }
        }
    };

    // ---- QK: 2 rounds x 32 channels
    float dots[9];
    #pragma unroll
    for (int n2 = 0; n2 < 9; ++n2) dots[n2] = 0.f;

    short8 pw0 = wload(0,0,0), pw1 = wload(0,0,1);   // prefetched first pair

    #pragma unroll
    for (int rr = 0; rr < 2; ++rr) {
        {
            short8 b0 = wload(0, 2*rr+1, 0), b1 = wload(0, 2*rr+1, 1);
            gemm_q(pw0, pw1, bload((2*rr)*16), 0);
            gemm_q(b0,  b1,  bload((2*rr+1)*16), 16);
            short8 c0 = wload(1, 2*rr,   0), c1 = wload(1, 2*rr,   1);
            short8 d0 = wload(1, 2*rr+1, 0), d1 = wload(1, 2*rr+1, 1);
            gemm_k(c0, c1, bload(64 + (2*rr)*16),  0);
            gemm_k(d0, d1, bload(64 + (2*rr+1)*16), 16);
        }
        __syncthreads();
        // prefetch next phase's first pair AFTER the barrier (drains at the
        // NEXT barrier; compiler emits vmcnt(0) at every s_barrier)
        if (rr == 0) { pw0 = wload(0, 2, 0); pw1 = wload(0, 2, 1); }
        else         { pw0 = wload(2, 0, 0); pw1 = wload(2, 0, 1); }
        if (oin) {
            uint4_ qa = *(const uint4_*)&qbuf2[t*KQ2];
            uint4_ qb = *(const uint4_*)&qbuf2[t*KQ2 + 8];
            uint4_ qc = *(const uint4_*)&qbuf2[t*KQ2 + 16];
            uint4_ qd = *(const uint4_*)&qbuf2[t*KQ2 + 24];
            #pragma unroll
            for (int n2 = 0; n2 < 9; ++n2) {
                int np = xpix + (n2/3 - 1)*XPW + (n2%3 - 1);
                uint4_ ka = *(const uint4_*)&kbuf2[np*KQ2];
                uint4_ kb = *(const uint4_*)&kbuf2[np*KQ2 + 8];
                uint4_ kc = *(const uint4_*)&kbuf2[np*KQ2 + 16];
                uint4_ kd = *(const uint4_*)&kbuf2[np*KQ2 + 24];
                // 4 independent 4-deep chains (was one 16-deep chain:
                // ~64 cy serial dep latency per neighbor)
                float sA = dots[n2], sB = 0.f, sC = 0.f, sD = 0.f;
                #pragma unroll
                for (int j = 0; j < 4; ++j) sA = dot2acc(qa[j], ka[j], sA);
                #pragma unroll
                for (int j = 0; j < 4; ++j) sB = dot2acc(qb[j], kb[j], sB);
                #pragma unroll
                for (int j = 0; j < 4; ++j) sC = dot2acc(qc[j], kc[j], sC);
                #pragma unroll
                for (int j = 0; j < 4; ++j) sD = dot2acc(qd[j], kd[j], sD);
                dots[n2] = (sA + sB) + (sC + sD);
            }
        }
        __syncthreads();
    }

    // ---- softmax (registers)
    float attn[9];
    if (oin) {
        float mx = -1e30f;
        #pragma unroll
        for (int n2 = 0; n2 < 9; ++n2) { dots[n2] *= 0.125f; mx = fmaxf(mx, dots[n2]); }
        float se = 0.f;
        #pragma unroll
        for (int n2 = 0; n2 < 9; ++n2) { attn[n2] = __expf(dots[n2] - mx); se += attn[n2]; }
        float inv = 1.f / se;
        #pragma unroll
        for (int n2 = 0; n2 < 9; ++n2) attn[n2] *= inv;
    }

    // ---- V: 2 rounds x 32 channels
    #pragma unroll
    for (int rr2 = 0; rr2 < 2; ++rr2) {
        {
            short8 b2 = wload(2, 2*rr2+1, 0), b3 = wload(2, 2*rr2+1, 1);
            gemm_v(pw0, pw1, bload(128 + (2*rr2)*16), 0);
            gemm_v(b2,  b3,  bload(128 + (2*rr2+1)*16), 16);
        }
        __syncthreads();
        if (rr2 == 0) { pw0 = wload(2, 2, 0); pw1 = wload(2, 2, 1); }
        if (t < NOP) {
            #pragma unroll
            for (int h2 = 0; h2 < 2; ++h2) {
                const int kg = rr2*2 + h2;           // 16-ch group 0..3
                short8 s0, s1;
                if (oin) {
                    float o1[16];
                    uint4_ r0 = __builtin_bit_cast(uint4_, resi[kg*2]);
                    uint4_ r1 = __builtin_bit_cast(uint4_, resi[kg*2 + 1]);
                    #pragma unroll
                    for (int j = 0; j < 4; ++j) {
                        o1[2*j]     = blo(r0[j]); o1[2*j + 1]     = bhi(r0[j]);
                        o1[8 + 2*j] = blo(r1[j]); o1[8 + 2*j + 1] = bhi(r1[j]);
                    }
                    #pragma unroll
                    for (int n2 = 0; n2 < 9; ++n2) {
                        float a = attn[n2];
                        int np = xpix + (n2/3 - 1)*XPW + (n2%3 - 1);
                        int sw = vswz(np);
                        uint4_ va = *(const uint4_*)&vbuf[np*VS + (((h2*2)   ^ sw) << 3)];
                        uint4_ vb = *(const uint4_*)&vbuf[np*VS + (((h2*2+1) ^ sw) << 3)];
                        #pragma unroll
                        for (int j = 0; j < 4; ++j) {
                            o1[2*j]         += a * blo(va[j]);
                            o1[2*j + 1]     += a * bhi(va[j]);
                            o1[8 + 2*j]     += a * blo(vb[j]);
                            o1[8 + 2*j + 1] += a * bhi(vb[j]);
                        }
                    }
                    #pragma unroll
                    for (int j = 0; j < 8; ++j) {
                        s0[j] = f2bs(o1[j]);
                        s1[j] = f2bs(o1[8 + j]);
                    }
                } else {
                    #pragma unroll
                    for (int j = 0; j < 8; ++j) { s0[j] = 0; s1[j] = 0; }  // conv zero-pad
                }
                *(short8*)&o1b[o1_idx(t, kg*16)]     = s0;
                *(short8*)&o1b[o1_idx(t, kg*16 + 8)] = s1;
            }
        }
        __syncthreads();
    }

    // ---- 3x3 conv 64->64 as one MFMA burst (K=576 tap-major), B from ws.
    // Weights loaded IN-LOOP (round-5 cw/nw rotation regressed; reverted).
    float4_ acc[4][2];
    #pragma unroll
    for (int nt = 0; nt < 4; ++nt) {
        acc[nt][0] = (float4_){0.f,0.f,0.f,0.f};
        acc[nt][1] = (float4_){0.f,0.f,0.f,0.f};
    }
    const int mtc0 = w*2, mtc1 = w*2 + 1;
    for (int ks = 0; ks < 18; ++ks) {
        int tap = ks >> 1;
        int dy = tap/3 - 1, dx = tap%3 - 1;
        int cin0 = (ks & 1)*32 + quad*8;
        int pixA = (mtc0 + 1 + dy)*OPW + (n16 + 1 + dx);
        int pixB = (mtc1 + 1 + dy)*OPW + (n16 + 1 + dx);
        short8 a0 = *(const short8*)&o1b[o1_idx(pixA, cin0)];
        short8 a1 = *(const short8*)&o1b[o1_idx(pixB, cin0)];
        #pragma unroll
        for (int nt = 0; nt < 4; ++nt) {
            short8 bb = *(const short8*)&wsm[((nt*18 + ks) << 9) + lane*8];
            acc[nt][0] = __builtin_amdgcn_mfma_f32_16x16x32_bf16(a0, bb, acc[nt][0], 0, 0, 0);
            acc[nt][1] = __builtin_amdgcn_mfma_f32_16x16x32_bf16(a1, bb, acc[nt][1], 0, 0, 0);
        }
    }
    __syncthreads();   // tbA/tbB overlap vbuf/o1b: all conv reads must land

    // ---- epilogue: two 32-ch halves through SEPARATE tbufs
    #pragma unroll
    for (int ntl = 0; ntl < 2; ++ntl)
        #pragma unroll
        for (int r = 0; r < 4; ++r) {
            tbA[(mtc0*16 + quad*4 + r)*TSF + ntl*16 + n16] = fmaxf(acc[ntl][0][r], 0.f);
            tbA[(mtc1*16 + quad*4 + r)*TSF + ntl*16 + n16] = fmaxf(acc[ntl][1][r], 0.f);
        }
    __syncthreads();
    {
        int pl = t & 127, oh = t >> 7;
        int ty_ = pl >> 4, tx_ = pl & 15;
        float* op = out + (size_t)b*CHW + (size_t)(oh*16)*HW
                    + (size_t)(gy0 + ty_)*WW + (gx0 + tx_);
        #pragma unroll
        for (int ii = 0; ii < 16; ++ii)
            op[(size_t)ii*HW] = tbA[pl*TSF + oh*16 + ii];
    }
    #pragma unroll
    for (int ntl = 0; ntl < 2; ++ntl)
        #pragma unroll
        for (int r = 0; r < 4; ++r) {
            tbB[(mtc0*16 + quad*4 + r)*TSF + ntl*16 + n16] = fmaxf(acc[2+ntl][0][r], 0.f);
            tbB[(mtc1*16 + quad*4 + r)*TSF + ntl*16 + n16] = fmaxf(acc[2+ntl][1][r], 0.f);
        }
    __syncthreads();
    {
        int pl = t & 127, oh = t >> 7;
        int ty_ = pl >> 4, tx_ = pl & 15;
        float* op = out + (size_t)b*CHW + (size_t)(32 + oh*16)*HW
                    + (size_t)(gy0 + ty_)*WW + (gx0 + tx_);
        #pragma unroll
        for (int ii = 0; ii < 16; ++ii)
            op[(size_t)ii*HW] = tbB[pl*TSF + oh*16 + ii];
    }
}

extern "C" void kernel_launch(void* const* d_in, const int* in_sizes, int n_in,
                              void* d_out, int out_size, void* d_ws, size_t ws_size,
                              hipStream_t stream) {
    const float* x    = (const float*)d_in[0];
    const float* wqkv = (const float*)d_in[1];
    const float* bqkv = (const float*)d_in[2];
    const float* wmlp = (const float*)d_in[3];
    float* outp = (float*)d_out;

    short* wsq = (short*)d_ws;                      // 24576 B
    short* wsm = wsq + WSQ_SHORTS;                  // 73728 B  (total 98304 B)

    prep_pack<<<128, 256, 0, stream>>>(wqkv, wmlp, wsq, wsm);

    dim3 grid(WW/TW, HH/TH, 4);
    fused_mfma<<<grid, 256, 0, stream>>>(x, wsq, bqkv, wsm, outp);
}